// Round 8
// baseline (155.550 us; speedup 1.0000x reference)
//
#include <hip/hip_runtime.h>

#define L 256
#define D 256
#define H 8
#define DH 32

static constexpr float NEGV = -4294967296.0f;       // fp32(-(2^32)+1)
static constexpr float INV_SQRT_DH = 0.17677669529663687f;  // 1/sqrt(32)

// ---------------------------------------------------------------------------
// Fused QKV projection: out = A @ W + bias (+ add)
// ---------------------------------------------------------------------------
__global__ __launch_bounds__(256) void proj3_kernel(
    const float* __restrict__ queries, const float* __restrict__ keys,
    const float* __restrict__ Wq, const float* __restrict__ bq,
    const float* __restrict__ Wk, const float* __restrict__ bk,
    const float* __restrict__ Wv, const float* __restrict__ bv,
    const float* __restrict__ pk, const float* __restrict__ pv,
    float* __restrict__ Qo, float* __restrict__ KPko, float* __restrict__ VPvo)
{
    __shared__ float As[16][68];
    __shared__ float Bs[16][64];

    const float* A; const float* W; const float* bias; const float* add; float* out;
    if (blockIdx.z == 0)      { A = queries; W = Wq; bias = bq; add = nullptr; out = Qo; }
    else if (blockIdx.z == 1) { A = keys;    W = Wk; bias = bk; add = pk;      out = KPko; }
    else                      { A = keys;    W = Wv; bias = bv; add = pv;      out = VPvo; }

    const int t  = threadIdx.x;
    const int bm = blockIdx.x * 64;
    const int bn = blockIdx.y * 64;

    const int ar = t >> 2;
    const int ak = (t & 3) << 2;
    const int br = t >> 4;
    const int bc = (t & 15) << 2;
    const int tm = (t >> 4) << 2;
    const int tn = (t & 15) << 2;

    float acc[4][4] = {};

    for (int k0 = 0; k0 < 256; k0 += 16) {
        const float4 a4 = *(const float4*)&A[(bm + ar) * 256 + k0 + ak];
        const float4 b4 = *(const float4*)&W[(k0 + br) * 256 + bn + bc];
        As[ak + 0][ar] = a4.x; As[ak + 1][ar] = a4.y;
        As[ak + 2][ar] = a4.z; As[ak + 3][ar] = a4.w;
        *(float4*)&Bs[br][bc] = b4;
        __syncthreads();

        #pragma unroll
        for (int kk = 0; kk < 16; ++kk) {
            const float4 a = *(const float4*)&As[kk][tm];
            const float4 bb = *(const float4*)&Bs[kk][tn];
            const float aa[4] = {a.x, a.y, a.z, a.w};
            const float bbv[4] = {bb.x, bb.y, bb.z, bb.w};
            #pragma unroll
            for (int i = 0; i < 4; ++i)
                #pragma unroll
                for (int jj = 0; jj < 4; ++jj)
                    acc[i][jj] = fmaf(aa[i], bbv[jj], acc[i][jj]);
        }
        __syncthreads();
    }

    const float4 bias4 = *(const float4*)&bias[bn + tn];
    #pragma unroll
    for (int i = 0; i < 4; ++i) {
        const int row = bm + tm + i;
        float4 o;
        o.x = acc[i][0] + bias4.x; o.y = acc[i][1] + bias4.y;
        o.z = acc[i][2] + bias4.z; o.w = acc[i][3] + bias4.w;
        if (add) {
            const float4 a4 = *(const float4*)&add[row * 256 + bn + tn];
            o.x += a4.x; o.y += a4.y; o.z += a4.z; o.w += a4.w;
        }
        *(float4*)&out[row * 256 + bn + tn] = o;
    }
}

// ---------------------------------------------------------------------------
// Row-sum masks.
// ---------------------------------------------------------------------------
__global__ __launch_bounds__(256) void mask_kernel(
    const float* __restrict__ keys, const float* __restrict__ queries,
    float* __restrict__ kmask, float* __restrict__ qmask)
{
    const int wid  = (blockIdx.x * 256 + threadIdx.x) >> 6;
    const int lane = threadIdx.x & 63;
    const float* src = (wid < 2048) ? keys : queries;
    const int row = (wid < 2048) ? wid : (wid - 2048);

    const float4 v = *(const float4*)&src[row * 256 + (lane << 2)];
    float s = v.x + v.y + v.z + v.w;
    #pragma unroll
    for (int o = 1; o < 64; o <<= 1) s += __shfl_xor(s, o);
    if (lane == 0) {
        const float m = (s != 0.0f) ? 1.0f : 0.0f;
        if (wid < 2048) kmask[row] = m; else qmask[row] = m;
    }
}

// ---------------------------------------------------------------------------
// Split-half online-softmax attention partials.
// Block (b, jj): half 0 = k in [0, s_a) of q=jj; half 1 = k in [s_b, q_b+1)
// of q_b=255-jj (s = ceil((q+1)/2)). Every block does exactly 128-129 rows.
// Per-lane partial (m, l, acc) written to ws; combine kernel merges.
// ---------------------------------------------------------------------------
__global__ __launch_bounds__(256) void attn_part_kernel(
    const float* __restrict__ Qm, const float* __restrict__ KPk,
    const float* __restrict__ VPv, const float* __restrict__ Tk,
    const float* __restrict__ Tv, const float* __restrict__ kmask,
    float* __restrict__ pm, float* __restrict__ pl, float4* __restrict__ pacc)
{
    const int bid = blockIdx.x;
    const int b   = bid >> 8;
    const int jj  = bid & 255;
    const int t    = threadIdx.x;
    const int w    = t >> 6;
    const int lane = t & 63;

    __shared__ float  kmrow[L];
    __shared__ float4 accL[4][64];
    __shared__ float  mL[4][64];
    __shared__ float  lL[4][64];

    kmrow[t] = kmask[(b << 8) + t];
    __syncthreads();

    #pragma unroll
    for (int half = 0; half < 2; ++half) {
        const int q   = half ? (255 - jj) : jj;
        const int bq  = (b << 8) + q;
        const int s   = (q + 2) >> 1;            // ceil((q+1)/2)
        const int klo = half ? s : 0;
        const int khi = half ? (q + 1) : s;
        const size_t tbase = (size_t)bq << 16;
        const float4 qv = *(const float4*)&Qm[bq * 256 + (lane << 2)];

        float  m  = NEGV;
        float  ls = 0.0f;
        float4 acc = make_float4(0.f, 0.f, 0.f, 0.f);

        #pragma unroll 2
        for (int k = klo + w; k < khi; k += 4) {
            const float4 kv  = *(const float4*)&KPk[((b << 8) + k) * 256 + (lane << 2)];
            const float4 tkv = *(const float4*)&Tk[tbase + ((size_t)k << 8) + (lane << 2)];
            const float4 vv  = *(const float4*)&VPv[((b << 8) + k) * 256 + (lane << 2)];
            const float4 tvv = *(const float4*)&Tv[tbase + ((size_t)k << 8) + (lane << 2)];

            float p = qv.x * (kv.x + tkv.x);
            p = fmaf(qv.y, kv.y + tkv.y, p);
            p = fmaf(qv.z, kv.z + tkv.z, p);
            p = fmaf(qv.w, kv.w + tkv.w, p);
            p += __shfl_xor(p, 1);
            p += __shfl_xor(p, 2);
            p += __shfl_xor(p, 4);

            const float sv = (kmrow[k] != 0.0f) ? p * INV_SQRT_DH : NEGV;
            const float mn = fmaxf(m, sv);
            const float f  = __expf(m - mn);
            const float e  = __expf(sv - mn);
            ls = fmaf(ls, f, e);
            acc.x = fmaf(e, vv.x + tvv.x, acc.x * f);
            acc.y = fmaf(e, vv.y + tvv.y, acc.y * f);
            acc.z = fmaf(e, vv.z + tvv.z, acc.z * f);
            acc.w = fmaf(e, vv.w + tvv.w, acc.w * f);
            m = mn;
        }

        accL[w][lane] = acc;
        mL[w][lane]   = m;
        lL[w][lane]   = ls;
        __syncthreads();

        if (t < 64) {
            const float m0 = mL[0][t], m1 = mL[1][t], m2 = mL[2][t], m3 = mL[3][t];
            const float M  = fmaxf(fmaxf(m0, m1), fmaxf(m2, m3));
            float li = 0.0f;
            float4 o = make_float4(0.f, 0.f, 0.f, 0.f);
            #pragma unroll
            for (int i = 0; i < 4; ++i) {
                const float f = __expf(mL[i][t] - M);
                li = fmaf(lL[i][t], f, li);
                const float4 a4 = accL[i][t];
                o.x = fmaf(a4.x, f, o.x);
                o.y = fmaf(a4.y, f, o.y);
                o.z = fmaf(a4.z, f, o.z);
                o.w = fmaf(a4.w, f, o.w);
            }
            const int idx = ((bq << 1) + half) << 6;   // [bq][half][lane]
            pm[idx + t]   = M;
            pl[idx + t]   = li;
            pacc[idx + t] = o;
        }
        __syncthreads();
    }
}

// ---------------------------------------------------------------------------
// Merge two halves per (b,q): softmax-merge + all-NEG uniform path + qmask
// + residual.
// ---------------------------------------------------------------------------
__global__ __launch_bounds__(64) void attn_comb_kernel(
    const float* __restrict__ pm, const float* __restrict__ pl,
    const float4* __restrict__ pacc, const float* __restrict__ VPv,
    const float* __restrict__ Tv, const float* __restrict__ qmask,
    const float* __restrict__ queries, float* __restrict__ out)
{
    const int bq = blockIdx.x;
    const int b  = bq >> 8;
    const int q  = bq & 255;
    const int t  = threadIdx.x;          // 0..63

    const int i0 = ((bq << 1) + 0) << 6;
    const int i1 = ((bq << 1) + 1) << 6;
    const float  m0 = pm[i0 + t], m1 = pm[i1 + t];
    const float  l0 = pl[i0 + t], l1 = pl[i1 + t];
    const float4 a0 = pacc[i0 + t], a1 = pacc[i1 + t];
    const float  M  = fmaxf(m0, m1);

    float li;
    float4 o;
    if (M == NEGV) {
        // fully-masked row: uniform attention over ALL 256 keys.
        // a0+a1 hold weight-1 sums over k in [0, q+1).
        o.x = a0.x + a1.x; o.y = a0.y + a1.y;
        o.z = a0.z + a1.z; o.w = a0.w + a1.w;
        const size_t tbase = (size_t)bq << 16;
        for (int k = q + 1; k < L; ++k) {
            const float4 vv  = *(const float4*)&VPv[((b << 8) + k) * 256 + (t << 2)];
            const float4 tvv = *(const float4*)&Tv[tbase + ((size_t)k << 8) + (t << 2)];
            o.x += vv.x + tvv.x;
            o.y += vv.y + tvv.y;
            o.z += vv.z + tvv.z;
            o.w += vv.w + tvv.w;
        }
        li = 256.0f;
    } else {
        const float f0 = __expf(m0 - M);
        const float f1 = __expf(m1 - M);
        li = fmaf(l0, f0, l1 * f1);
        o.x = fmaf(a0.x, f0, a1.x * f1);
        o.y = fmaf(a0.y, f0, a1.y * f1);
        o.z = fmaf(a0.z, f0, a1.z * f1);
        o.w = fmaf(a0.w, f0, a1.w * f1);
    }

    const float r   = 1.0f / li;
    const float qmv = qmask[bq];
    const float4 qv = *(const float4*)&queries[bq * 256 + (t << 2)];
    float4 ov;
    ov.x = o.x * r * qmv + qv.x;
    ov.y = o.y * r * qmv + qv.y;
    ov.z = o.z * r * qmv + qv.z;
    ov.w = o.w * r * qmv + qv.w;
    *(float4*)&out[bq * 256 + (t << 2)] = ov;
}

// ---------------------------------------------------------------------------
extern "C" void kernel_launch(void* const* d_in, const int* in_sizes, int n_in,
                              void* d_out, int out_size, void* d_ws, size_t ws_size,
                              hipStream_t stream)
{
    const float* queries = (const float*)d_in[0];
    const float* keys    = (const float*)d_in[1];
    const float* Tk      = (const float*)d_in[2];
    const float* Tv      = (const float*)d_in[3];
    const float* pk      = (const float*)d_in[4];
    const float* pv      = (const float*)d_in[5];
    const float* Wq      = (const float*)d_in[6];
    const float* bq      = (const float*)d_in[7];
    const float* Wk      = (const float*)d_in[8];
    const float* bk      = (const float*)d_in[9];
    const float* Wv      = (const float*)d_in[10];
    const float* bv      = (const float*)d_in[11];
    float* out = (float*)d_out;

    float*  ws   = (float*)d_ws;
    float*  Q    = ws;                    // 524288
    float*  KPk  = ws + 524288;           // 524288
    float*  VPv  = ws + 1048576;          // 524288
    float*  km   = ws + 1572864;          // 2048
    float*  qm   = ws + 1574912;          // 2048
    float*  pm   = ws + 1576960;          // 2048*2*64 = 262144
    float*  pl   = ws + 1839104;          // 262144
    float4* pacc = (float4*)(ws + 2101248); // 2048*2*64 float4 = 1048576 floats

    dim3 pgrid(2048 / 64, 256 / 64, 3);
    proj3_kernel<<<pgrid, 256, 0, stream>>>(queries, keys, Wq, bq, Wk, bk,
                                            Wv, bv, pk, pv, Q, KPk, VPv);
    mask_kernel<<<1024, 256, 0, stream>>>(keys, queries, km, qm);
    attn_part_kernel<<<2048, 256, 0, stream>>>(Q, KPk, VPv, Tk, Tv, km,
                                               pm, pl, pacc);
    attn_comb_kernel<<<2048, 64, 0, stream>>>(pm, pl, pacc, VPv, Tv, qm,
                                              queries, out);
}